// Round 6
// baseline (48325.375 us; speedup 1.0000x reference)
//
#include <hip/hip_runtime.h>
#include <stdint.h>

#define SEQ   512
#define BATCH 64
#define INP   64
#define HID   1024
#define NBLK  512     // 256 layer-0 + 256 layer-1 blocks (wavefront pipeline)
#define NTHR  256     // 4 units x 64 batch  (256 blocks x 4 units = 1024 = HID)
#define CHK   32      // h k-values staged per chunk (8 KB)
#define NCH   (HID / CHK)   // 32 chunks, processed 2 per unrolled iter (banks A/B)

typedef float f4 __attribute__((ext_vector_type(4)));

// ---- coherent x4 load: bypasses L1 (sc0) and non-coherent per-XCD L2 (sc1) ----
// Caller manages s_waitcnt vmcnt(N) explicitly (counted waits, T4 pattern).
// NOTE: these asm loads are invisible to the compiler's waitcnt-insertion pass,
// so __syncthreads does NOT drain them — the prefetch survives the barriers.
__device__ __forceinline__ void cload4(f4* dst, const float* p) {
    asm volatile("global_load_dwordx4 %0, %1, off sc0 sc1"
                 : "=&v"(*dst) : "v"(p) : "memory");
}
#define WAITVM(n) do { asm volatile("s_waitcnt vmcnt(" #n ")" ::: "memory"); \
                       __builtin_amdgcn_sched_barrier(0); } while (0)

// ---- agent-scope coherent dword access (stores / single loads) ----
__device__ __forceinline__ float cload(float* p) {
    return __hip_atomic_load(p, __ATOMIC_RELAXED, __HIP_MEMORY_SCOPE_AGENT);
}
__device__ __forceinline__ void cstore(float* p, float v) {
    __hip_atomic_store(p, v, __ATOMIC_RELAXED, __HIP_MEMORY_SCOPE_AGENT);
}

__device__ __forceinline__ float sigf(float x) { return 1.0f / (1.0f + __expf(-x)); }

// ---- one-time flag barrier (poison-safe window check, proven r2/r4) ----
__device__ __forceinline__ void flagbar(uint32_t* flags, int tid) {
    __syncthreads();
    if (tid == 0)
        __hip_atomic_store(&flags[blockIdx.x], 1u, __ATOMIC_RELAXED, __HIP_MEMORY_SCOPE_AGENT);
    if (tid < 64) {
        for (;;) {
            bool ok = true;
            #pragma unroll
            for (int i = 0; i < NBLK / 64; ++i) {
                uint32_t v = __hip_atomic_load(&flags[tid + i * 64], __ATOMIC_RELAXED,
                                               __HIP_MEMORY_SCOPE_AGENT);
                ok &= ((uint32_t)(v - 1u) < 0x10000000u);
            }
            if (__all(ok)) break;
        }
    }
    __syncthreads();
}

// ---- per-round counter barrier (proven r4): 8 monotonic group counters ----
__device__ __forceinline__ void bar_arrive(uint32_t* grp, int tid) {
    __syncthreads();   // drains all waves' tracked stores (vmcnt(0) before s_barrier)
    if (tid == 0)
        __hip_atomic_fetch_add(&grp[blockIdx.x & 7], 1u, __ATOMIC_RELAXED,
                               __HIP_MEMORY_SCOPE_AGENT);
}
__device__ __forceinline__ void bar_wait(uint32_t* grp, uint32_t target, int tid) {
    if (tid < 64) {
        for (;;) {
            uint32_t v = __hip_atomic_load(&grp[tid & 7], __ATOMIC_RELAXED,
                                           __HIP_MEMORY_SCOPE_AGENT);
            if (__all((uint32_t)(v - target) < 0x10000000u)) break;
        }
    }
    __syncthreads();
}

// ============ fused wavefront kernel (r4 geometry, x4-coherent 2-deep staging) ============
__global__ void __launch_bounds__(NTHR, 2) lstm_fused(
    const float* __restrict__ x,
    const float* __restrict__ Wih0, const float* __restrict__ Whh0,
    const float* __restrict__ bih0, const float* __restrict__ bhh0,
    const float* __restrict__ Wih1, const float* __restrict__ Whh1,
    const float* __restrict__ bih1, const float* __restrict__ bhh1,
    float* __restrict__ out, float* __restrict__ h0buf, float* __restrict__ h2buf,
    uint32_t* __restrict__ flags, uint32_t* __restrict__ grp)
{
    __shared__ float Wsh[4][HID][4];   // 64 KB: Whh slice (4 units x 4 gates)
    __shared__ float st1[CHK * 64];    // 8 KB: h0-chunk (L0) / h1-chunk (L1)
    __shared__ float st2[CHK * 64];    // 8 KB: h2-chunk (L1 only)
    const int tid = threadIdx.x;
    const int bk  = blockIdx.x;
    const bool Lb = (bk >= NBLK / 2);
    const int ub  = (Lb ? bk - NBLK / 2 : bk) * 4;
    const int u   = tid >> 6;
    const int b   = tid & 63;
    const int j   = ub + u;
    const int js  = ub + __builtin_amdgcn_readfirstlane(u);

    const float* Whh = Lb ? Whh1 : Whh0;
    for (int idx = tid; idx < 4 * 4 * HID; idx += NTHR) {
        int uu = idx >> 12, g = (idx >> 10) & 3, k = idx & (HID - 1);
        Wsh[uu][k][g] = Whh[((size_t)(g * HID + ub + uu)) * HID + k];
    }
    const float* bi = Lb ? bih1 : bih0;
    const float* bh = Lb ? bhh1 : bhh0;
    const float bias0 = bi[0 * HID + j] + bh[0 * HID + j];
    const float bias1 = bi[1 * HID + j] + bh[1 * HID + j];
    const float bias2 = bi[2 * HID + j] + bh[2 * HID + j];
    const float bias3 = bi[3 * HID + j] + bh[3 * HID + j];

    cstore((Lb ? h2buf : h0buf) + j * 64 + b, 0.0f);
    if (bk < 8 && tid == 0) {
        __hip_atomic_store(&grp[bk], 0u, __ATOMIC_RELAXED, __HIP_MEMORY_SCOPE_AGENT);
        __threadfence();
    }
    float c = 0.0f;
    flagbar(flags, tid);   // barrier q=1

    if (!Lb) {
        // ---- layer 0: compute step t, arrive(t+2), xpart(t+1), wait(t+2) ----
        const float4* wi0 = (const float4*)(Wih0 + (size_t)(0 * HID + js) * INP);
        const float4* wi1 = (const float4*)(Wih0 + (size_t)(1 * HID + js) * INP);
        const float4* wi2 = (const float4*)(Wih0 + (size_t)(2 * HID + js) * INP);
        const float4* wi3 = (const float4*)(Wih0 + (size_t)(3 * HID + js) * INP);
        float a0 = bias0, a1 = bias1, a2 = bias2, a3 = bias3;
        {   // xpart(0)
            const float4* xr = (const float4*)(x + (size_t)b * INP);
            #pragma unroll
            for (int k4 = 0; k4 < INP / 4; ++k4) {
                float4 xv = xr[k4];
                float4 u0 = wi0[k4], u1 = wi1[k4], u2 = wi2[k4], u3 = wi3[k4];
                a0 += u0.x * xv.x + u0.y * xv.y + u0.z * xv.z + u0.w * xv.w;
                a1 += u1.x * xv.x + u1.y * xv.y + u1.z * xv.z + u1.w * xv.w;
                a2 += u2.x * xv.x + u2.y * xv.y + u2.z * xv.z + u2.w * xv.w;
                a3 += u3.x * xv.x + u3.y * xv.y + u3.z * xv.z + u3.w * xv.w;
            }
        }
        for (int t = 0; t < SEQ; ++t) {
            // invariant: wait(t+1) passed; a0..a3 = bias + xpart(t); h1[t-1] in hr
            float* hr = h0buf + (t & 1) * (HID * 64);
            float* hw = h0buf + ((t & 1) ^ 1) * (HID * 64);
            f4 pA[2], pB[2];
            // prologue: chunk 0 -> bank A, chunk 1 -> bank B (2-deep pipeline)
            cload4(&pA[0], hr + 0 * 2048 +    0 + tid * 4);
            cload4(&pA[1], hr + 0 * 2048 + 1024 + tid * 4);
            cload4(&pB[0], hr + 1 * 2048 +    0 + tid * 4);
            cload4(&pB[1], hr + 1 * 2048 + 1024 + tid * 4);
            for (int cc = 0; cc < NCH; cc += 2) {
                // --- even chunk cc (bank A) ---
                __syncthreads();                    // prev chunk consumed, st1 free
                WAITVM(2);                          // bank A ready (B stays in flight)
                *(f4*)&st1[   0 + tid * 4] = pA[0];
                *(f4*)&st1[1024 + tid * 4] = pA[1];
                if (cc + 2 < NCH) {
                    cload4(&pA[0], hr + (cc + 2) * 2048 +    0 + tid * 4);
                    cload4(&pA[1], hr + (cc + 2) * 2048 + 1024 + tid * 4);
                }
                __syncthreads();                    // stage visible
                #pragma unroll
                for (int kk = 0; kk < CHK; ++kk) {
                    int k = cc * CHK + kk;
                    float  hv = st1[kk * 64 + b];
                    float4 w  = *(const float4*)&Wsh[u][k][0];
                    a0 += w.x * hv; a1 += w.y * hv; a2 += w.z * hv; a3 += w.w * hv;
                }
                // --- odd chunk cc+1 (bank B) ---
                __syncthreads();
                if (cc + 2 < NCH) { WAITVM(2); } else { WAITVM(0); }
                *(f4*)&st1[   0 + tid * 4] = pB[0];
                *(f4*)&st1[1024 + tid * 4] = pB[1];
                if (cc + 3 < NCH) {
                    cload4(&pB[0], hr + (cc + 3) * 2048 +    0 + tid * 4);
                    cload4(&pB[1], hr + (cc + 3) * 2048 + 1024 + tid * 4);
                }
                __syncthreads();
                #pragma unroll
                for (int kk = 0; kk < CHK; ++kk) {
                    int k = (cc + 1) * CHK + kk;
                    float  hv = st1[kk * 64 + b];
                    float4 w  = *(const float4*)&Wsh[u][k][0];
                    a0 += w.x * hv; a1 += w.y * hv; a2 += w.z * hv; a3 += w.w * hv;
                }
            }
            float ig = sigf(a0), fg = sigf(a1), gg = tanhf(a2), og = sigf(a3);
            c = fg * c + ig * gg;
            float h = og * tanhf(c);
            cstore(hw + j * 64 + b, h);          // h1_t: read by L0(t+1) and L1(t)
            bar_arrive(grp, tid);                // barrier q=t+2
            if (t + 1 < SEQ) {
                a0 = bias0; a1 = bias1; a2 = bias2; a3 = bias3;
                const float4* xr = (const float4*)(x + ((size_t)(t + 1) * BATCH + b) * INP);
                #pragma unroll
                for (int k4 = 0; k4 < INP / 4; ++k4) {
                    float4 xv = xr[k4];
                    float4 u0 = wi0[k4], u1 = wi1[k4], u2 = wi2[k4], u3 = wi3[k4];
                    a0 += u0.x * xv.x + u0.y * xv.y + u0.z * xv.z + u0.w * xv.w;
                    a1 += u1.x * xv.x + u1.y * xv.y + u1.z * xv.z + u1.w * xv.w;
                    a2 += u2.x * xv.x + u2.y * xv.y + u2.z * xv.z + u2.w * xv.w;
                    a3 += u3.x * xv.x + u3.y * xv.y + u3.z * xv.z + u3.w * xv.w;
                }
                bar_wait(grp, (uint32_t)(t + 1) * 64u, tid);   // wait q=t+2
            }
        }
    } else {
        // ---- layer 1: arrive(t+2), wait(t+2), compute step t ----
        const float* wr0 = Wih1 + (size_t)(0 * HID + js) * HID;   // wave-uniform rows
        const float* wr1 = Wih1 + (size_t)(1 * HID + js) * HID;
        const float* wr2 = Wih1 + (size_t)(2 * HID + js) * HID;
        const float* wr3 = Wih1 + (size_t)(3 * HID + js) * HID;
        for (int t = 0; t < SEQ; ++t) {
            bar_arrive(grp, tid);                          // h2[t-1] stores drained
            bar_wait(grp, (uint32_t)(t + 1) * 64u, tid);   // h1_t visible
            float* h1r = h0buf + ((t & 1) ^ 1) * (HID * 64);   // h1_t
            float* h2r = h2buf + (t & 1) * (HID * 64);
            float* h2w = h2buf + ((t & 1) ^ 1) * (HID * 64);
            float a0 = bias0, a1 = bias1, a2 = bias2, a3 = bias3;
            f4 p1A[2], p1B[2], p2A[2], p2B[2];
            // prologue: chunk 0 -> bank A, chunk 1 -> bank B (4 loads per bank)
            cload4(&p1A[0], h1r +    0 + tid * 4);  cload4(&p1A[1], h1r + 1024 + tid * 4);
            cload4(&p2A[0], h2r +    0 + tid * 4);  cload4(&p2A[1], h2r + 1024 + tid * 4);
            cload4(&p1B[0], h1r + 2048 + tid * 4);  cload4(&p1B[1], h1r + 3072 + tid * 4);
            cload4(&p2B[0], h2r + 2048 + tid * 4);  cload4(&p2B[1], h2r + 3072 + tid * 4);
            for (int cc = 0; cc < NCH; cc += 2) {
                // --- even chunk cc (bank A) ---
                __syncthreads();
                WAITVM(4);                          // bank A ready (B in flight)
                *(f4*)&st1[   0 + tid * 4] = p1A[0];
                *(f4*)&st1[1024 + tid * 4] = p1A[1];
                *(f4*)&st2[   0 + tid * 4] = p2A[0];
                *(f4*)&st2[1024 + tid * 4] = p2A[1];
                if (cc + 2 < NCH) {
                    const float* s1 = h1r + (cc + 2) * 2048;
                    const float* s2 = h2r + (cc + 2) * 2048;
                    cload4(&p1A[0], s1 +    0 + tid * 4);  cload4(&p1A[1], s1 + 1024 + tid * 4);
                    cload4(&p2A[0], s2 +    0 + tid * 4);  cload4(&p2A[1], s2 + 1024 + tid * 4);
                }
                __syncthreads();
                #pragma unroll
                for (int kk = 0; kk < CHK; ++kk) {
                    int k = cc * CHK + kk;
                    float  x1 = st1[kk * 64 + b];
                    float  hv = st2[kk * 64 + b];
                    float4 wh = *(const float4*)&Wsh[u][k][0];
                    a0 += wh.x * hv + wr0[k] * x1;
                    a1 += wh.y * hv + wr1[k] * x1;
                    a2 += wh.z * hv + wr2[k] * x1;
                    a3 += wh.w * hv + wr3[k] * x1;
                }
                // --- odd chunk cc+1 (bank B) ---
                __syncthreads();
                if (cc + 2 < NCH) { WAITVM(4); } else { WAITVM(0); }
                *(f4*)&st1[   0 + tid * 4] = p1B[0];
                *(f4*)&st1[1024 + tid * 4] = p1B[1];
                *(f4*)&st2[   0 + tid * 4] = p2B[0];
                *(f4*)&st2[1024 + tid * 4] = p2B[1];
                if (cc + 3 < NCH) {
                    const float* s1 = h1r + (cc + 3) * 2048;
                    const float* s2 = h2r + (cc + 3) * 2048;
                    cload4(&p1B[0], s1 +    0 + tid * 4);  cload4(&p1B[1], s1 + 1024 + tid * 4);
                    cload4(&p2B[0], s2 +    0 + tid * 4);  cload4(&p2B[1], s2 + 1024 + tid * 4);
                }
                __syncthreads();
                #pragma unroll
                for (int kk = 0; kk < CHK; ++kk) {
                    int k = (cc + 1) * CHK + kk;
                    float  x1 = st1[kk * 64 + b];
                    float  hv = st2[kk * 64 + b];
                    float4 wh = *(const float4*)&Wsh[u][k][0];
                    a0 += wh.x * hv + wr0[k] * x1;
                    a1 += wh.y * hv + wr1[k] * x1;
                    a2 += wh.z * hv + wr2[k] * x1;
                    a3 += wh.w * hv + wr3[k] * x1;
                }
            }
            float ig = sigf(a0), fg = sigf(a1), gg = tanhf(a2), og = sigf(a3);
            c = fg * c + ig * gg;
            float h = og * tanhf(c);
            cstore(h2w + j * 64 + b, h);                // recurrent state, coherent
            out[((size_t)t * BATCH + b) * HID + j] = h; // final output, plain store
        }
    }
}

// ============ epilogue: y_pred = h2[T-1] @ Wlin^T + b ============
__global__ void lstm_finalize(const float* __restrict__ Wlin, const float* __restrict__ blin,
                              float* __restrict__ out, float* __restrict__ h2buf)
{
    __shared__ float red[256];
    const int b = blockIdx.x, tid = threadIdx.x;
    float p = 0.0f;
    for (int k = tid; k < HID; k += 256) p += cload(h2buf + k * 64 + b) * Wlin[k];
    red[tid] = p;
    __syncthreads();
    for (int s = 128; s > 0; s >>= 1) {
        if (tid < s) red[tid] += red[tid + s];
        __syncthreads();
    }
    if (tid == 0) out[(size_t)SEQ * BATCH * HID + b] = blin[0] + red[0];
}

extern "C" void kernel_launch(void* const* d_in, const int* in_sizes, int n_in,
                              void* d_out, int out_size, void* d_ws, size_t ws_size,
                              hipStream_t stream) {
    const float* x     = (const float*)d_in[0];
    const float* Wih0  = (const float*)d_in[1];
    const float* Whh0  = (const float*)d_in[2];
    const float* bih0  = (const float*)d_in[3];
    const float* bhh0  = (const float*)d_in[4];
    const float* Wih1  = (const float*)d_in[5];
    const float* Whh1  = (const float*)d_in[6];
    const float* bih1  = (const float*)d_in[7];
    const float* bhh1  = (const float*)d_in[8];
    const float* Wlin  = (const float*)d_in[9];
    const float* blin  = (const float*)d_in[10];
    float* out = (float*)d_out;

    float* ws = (float*)d_ws;
    float* h0buf = ws;                       // 2 * 1024 * 64 floats (h1 ping-pong)
    float* h2buf = ws + 2 * HID * BATCH;     // 2 * 1024 * 64 floats (h2 ping-pong)
    uint32_t* flags = (uint32_t*)(ws + 4 * HID * BATCH);   // 512 u32 (init barrier)
    uint32_t* grp   = flags + NBLK;                         // 8 u32 (round counters)

    lstm_fused<<<dim3(NBLK), dim3(NTHR), 0, stream>>>(
        x, Wih0, Whh0, bih0, bhh0, Wih1, Whh1, bih1, bhh1, out, h0buf, h2buf, flags, grp);
    lstm_finalize<<<dim3(BATCH), dim3(256), 0, stream>>>(Wlin, blin, out, h2buf);
}